// Round 2
// baseline (120.063 us; speedup 1.0000x reference)
//
#include <hip/hip_runtime.h>

#define BB 8192
#define NN 36
#define INF_ 8
#define HH 8
#define DHH 9
#define GATF 72
#define ACTF 10
#define NEGV -1000000000.0f

// LDS strides
#define HSTRIDE 12   // h row stride in floats (16B-aligned rows)
#define GSTRIDE 73   // g row stride (odd -> bank-conflict-free column walks)

__global__ __launch_bounds__(256) void gnn_kernel(
    const float* __restrict__ x, const int* __restrict__ adj,
    const float* __restrict__ W, const float* __restrict__ a_src,
    const float* __restrict__ a_dst, const float* __restrict__ W_down,
    const float* __restrict__ b_down, const float* __restrict__ W_mu,
    const float* __restrict__ b_mu, float* __restrict__ out)
{
    const int b = blockIdx.x;
    const int tid = threadIdx.x;

    __shared__ float xcs[NN * 8];                       // xc padded to 8
    __shared__ float ts[NN];                            // t = x[:,:,4]
    __shared__ __align__(16) float hbuf[HH * NN * HSTRIDE];
    __shared__ float es[HH * NN];
    __shared__ float ed[HH * NN];
    __shared__ float adjneg[NN * NN];                   // 0 or NEG
    __shared__ float gbuf[NN * GSTRIDE];
    __shared__ float feat[GATF];
    // staged weights
    __shared__ float wlds[HH * 7 * DHH];                // 504
    __shared__ float aslds[HH * DHH];                   // 72
    __shared__ float adlds[HH * DHH];                   // 72
    __shared__ float wdlds[GATF];                       // 72
    __shared__ float wmulds[GATF * ACTF];               // 720
    __shared__ float bdlds[1];
    __shared__ float bmulds[ACTF];

    // ---- Phase 0: stage inputs ----
    const float* xb = x + (size_t)b * (NN * INF_);
    for (int idx = tid; idx < NN * INF_; idx += 256) {
        int n = idx / INF_, c = idx - n * INF_;
        float v = xb[idx];
        if (c < 3) xcs[n * 8 + c] = v;
        else if (c > 3) xcs[n * 8 + (c - 1)] = v;
        if (c == 4) ts[n] = v;
    }
    for (int idx = tid; idx < NN * NN; idx += 256)
        adjneg[idx] = (adj[idx] > 0) ? 0.0f : NEGV;
    for (int idx = tid; idx < HH * 7 * DHH; idx += 256) wlds[idx] = W[idx];
    if (tid < HH * DHH) { aslds[tid] = a_src[tid]; adlds[tid] = a_dst[tid]; }
    if (tid >= 128 && tid < 128 + GATF) wdlds[tid - 128] = W_down[tid - 128];
    for (int idx = tid; idx < GATF * ACTF; idx += 256) wmulds[idx] = W_mu[idx];
    if (tid == 0) bdlds[0] = b_down[0];
    if (tid >= 64 && tid < 64 + ACTF) bmulds[tid - 64] = b_mu[tid - 64];
    __syncthreads();

    // ---- Phase 1: h = einsum('ni,hid->hnd', xc, W), stored [h][n][d] stride 12 ----
    for (int v = tid; v < HH * NN * DHH; v += 256) {
        int hh = v / (NN * DHH);
        int rem = v - hh * (NN * DHH);
        int n = rem / DHH, d = rem - n * DHH;
        const float* wp = wlds + hh * (7 * DHH) + d;
        const float* xp = xcs + n * 8;
        float acc = 0.f;
        #pragma unroll
        for (int i = 0; i < 7; ++i) acc += xp[i] * wp[i * DHH];
        hbuf[(hh * NN + n) * HSTRIDE + d] = acc;
    }
    __syncthreads();

    // ---- Phase 2: e_src, e_dst (288 rows > 256 threads -> grid-stride!) ----
    for (int r = tid; r < HH * NN; r += 256) {
        int hh = r / NN;
        const float* hp = hbuf + r * HSTRIDE;
        const float* asp = aslds + hh * DHH;
        const float* adp = adlds + hh * DHH;
        float s = 0.f, dd = 0.f;
        #pragma unroll
        for (int d = 0; d < DHH; ++d) { float hv = hp[d]; s += hv * asp[d]; dd += hv * adp[d]; }
        es[r] = s; ed[r] = dd;
    }
    __syncthreads();

    // ---- Phase 3: attention rows; one (h,i) row per thread ----
    for (int r = tid; r < HH * NN; r += 256) {
        int hh = r / NN, i = r - hh * NN;
        float esi = es[r];
        const float* edp = ed + hh * NN;
        const float* ajp = adjneg + i * NN;
        float ev[NN];
        float m = -3.4e38f;
        #pragma unroll
        for (int j = 0; j < NN; ++j) {
            float e = esi + edp[j];
            e = (e > 0.f) ? e : 0.2f * e;      // leaky_relu 0.2
            e += ajp[j];                        // additive mask (0 or -1e9)
            ev[j] = e;
            m = fmaxf(m, e);
        }
        float s = 0.f;
        #pragma unroll
        for (int j = 0; j < NN; ++j) {
            float p = __expf(ev[j] - m);
            ev[j] = p;
            s += p;
        }
        float inv = 1.0f / s;
        float acc[DHH];
        #pragma unroll
        for (int d = 0; d < DHH; ++d) acc[d] = 0.f;
        const float* hrow = hbuf + (hh * NN) * HSTRIDE;
        #pragma unroll
        for (int j = 0; j < NN; ++j) {
            float p = ev[j];
            const float* hj = hrow + j * HSTRIDE;
            float4 h0 = *reinterpret_cast<const float4*>(hj);
            float4 h1 = *reinterpret_cast<const float4*>(hj + 4);
            float h2 = hj[8];
            acc[0] += p * h0.x; acc[1] += p * h0.y; acc[2] += p * h0.z; acc[3] += p * h0.w;
            acc[4] += p * h1.x; acc[5] += p * h1.y; acc[6] += p * h1.z; acc[7] += p * h1.w;
            acc[8] += p * h2;
        }
        float* gp = gbuf + i * GSTRIDE + hh * DHH;
        #pragma unroll
        for (int d = 0; d < DHH; ++d) {
            float o = acc[d] * inv;
            gp[d] = (o > 0.f) ? o : (__expf(o) - 1.0f);   // elu
        }
    }
    __syncthreads();

    // ---- Phase 4: down-projection + feat = leaky_relu(concat(down, t), 0.01) ----
    if (tid < NN) {
        const float* gp = gbuf + tid * GSTRIDE;
        float acc = bdlds[0];
        #pragma unroll
        for (int k = 0; k < GATF; ++k) acc += gp[k] * wdlds[k];
        feat[tid] = (acc > 0.f) ? acc : 0.01f * acc;
    } else if (tid < 2 * NN) {
        float v = ts[tid - NN];
        feat[tid] = (v > 0.f) ? v : 0.01f * v;
    }
    __syncthreads();

    // ---- Phase 5: mu = feat @ W_mu + b_mu ----
    if (tid < ACTF) {
        float acc = bmulds[tid];
        #pragma unroll
        for (int k = 0; k < GATF; ++k) acc += feat[k] * wmulds[k * ACTF + tid];
        out[(size_t)b * ACTF + tid] = acc;
    }
}

extern "C" void kernel_launch(void* const* d_in, const int* in_sizes, int n_in,
                              void* d_out, int out_size, void* d_ws, size_t ws_size,
                              hipStream_t stream) {
    const float* x      = (const float*)d_in[0];
    const int*   adj    = (const int*)d_in[1];
    const float* W      = (const float*)d_in[2];
    const float* a_src  = (const float*)d_in[3];
    const float* a_dst  = (const float*)d_in[4];
    const float* W_down = (const float*)d_in[5];
    const float* b_down = (const float*)d_in[6];
    const float* W_mu   = (const float*)d_in[7];
    const float* b_mu   = (const float*)d_in[8];
    float* out = (float*)d_out;

    gnn_kernel<<<BB, 256, 0, stream>>>(x, adj, W, a_src, a_dst, W_down, b_down, W_mu, b_mu, out);
}

// Round 4
// 118.362 us; speedup vs baseline: 1.0144x; 1.0144x over previous
//
#include <hip/hip_runtime.h>

#define BB 8192
#define NN 36
#define INF_ 8
#define HH 8
#define DHH 9
#define GATF 72
#define ACTF 10
#define NTH 320

#define HSTRIDE 12   // h row stride in floats (16B-aligned rows)

__global__ __launch_bounds__(NTH, 6) void gnn_kernel(
    const float* __restrict__ x, const int* __restrict__ adj,
    const float* __restrict__ W, const float* __restrict__ a_src,
    const float* __restrict__ a_dst, const float* __restrict__ W_down,
    const float* __restrict__ b_down, const float* __restrict__ W_mu,
    const float* __restrict__ b_mu, float* __restrict__ out)
{
    const int b = blockIdx.x;
    const int tid = threadIdx.x;

    __shared__ float xcs[NN * 8];                       // xc padded to 8
    __shared__ float ts[NN];                            // t = x[:,:,4]
    __shared__ __align__(16) float hbuf[HH * NN * HSTRIDE];  // 13824 B
    __shared__ float es[HH * NN];
    __shared__ float ed[HH * NN];
    __shared__ uint2 adjm[NN];                          // row bitmasks
    __shared__ float pd[NN * 9];                        // partial down, [i][h] stride 9
    __shared__ float feat[GATF];
    // staged weights
    __shared__ float wlds[HH * 7 * DHH];                // 504
    __shared__ float aslds[HH * DHH];                   // 72
    __shared__ float adlds[HH * DHH];                   // 72
    __shared__ float wdlds[GATF];                       // 72
    __shared__ float wmulds[GATF * ACTF];               // 720
    __shared__ float bdlds[1];
    __shared__ float bmulds[ACTF];

    // ---- Phase 0: stage inputs ----
    const float* xb = x + (size_t)b * (NN * INF_);
    if (tid < NN * INF_) {
        int n = tid >> 3, c = tid & 7;
        float v = xb[tid];
        if (c < 3) xcs[n * 8 + c] = v;
        else if (c > 3) xcs[n * 8 + (c - 1)] = v;
        if (c == 4) ts[n] = v;
    }
    // adjacency -> 36 row bitmasks on threads 256..291 (fits within NTH=320)
    {
        int i = tid - 256;
        if (i >= 0 && i < NN) {
            const int4* ap = reinterpret_cast<const int4*>(adj + i * NN);  // 144B rows, 16B-aligned
            unsigned int lo = 0u, hi = 0u;
            #pragma unroll
            for (int q = 0; q < 9; ++q) {
                int4 a4 = ap[q];
                const int base = q * 4;
                if (base + 0 < 32) { lo |= (a4.x > 0 ? 1u << (base + 0) : 0u); } else { hi |= (a4.x > 0 ? 1u << (base - 32) : 0u); }
                if (base + 1 < 32) { lo |= (a4.y > 0 ? 1u << (base + 1) : 0u); } else { hi |= (a4.y > 0 ? 1u << (base + 1 - 32) : 0u); }
                if (base + 2 < 32) { lo |= (a4.z > 0 ? 1u << (base + 2) : 0u); } else { hi |= (a4.z > 0 ? 1u << (base + 2 - 32) : 0u); }
                if (base + 3 < 32) { lo |= (a4.w > 0 ? 1u << (base + 3) : 0u); } else { hi |= (a4.w > 0 ? 1u << (base + 3 - 32) : 0u); }
            }
            adjm[i] = make_uint2(lo, hi);
        }
    }
    for (int idx = tid; idx < HH * 7 * DHH; idx += NTH) wlds[idx] = W[idx];
    if (tid < HH * DHH) { aslds[tid] = a_src[tid]; adlds[tid] = a_dst[tid]; }
    if (tid >= 128 && tid < 128 + GATF) wdlds[tid - 128] = W_down[tid - 128];
    for (int idx = tid; idx < GATF * ACTF; idx += NTH) wmulds[idx] = W_mu[idx];
    if (tid == 0) bdlds[0] = b_down[0];
    if (tid >= 64 && tid < 64 + ACTF) bmulds[tid - 64] = b_mu[tid - 64];
    __syncthreads();

    // ---- Phase 1: h = einsum('ni,hid->hnd', xc, W), stored [h][n][d] stride 12 ----
    for (int v = tid; v < HH * NN * DHH; v += NTH) {
        int hh = v / (NN * DHH);
        int rem = v - hh * (NN * DHH);
        int n = rem / DHH, d = rem - n * DHH;
        const float* wp = wlds + hh * (7 * DHH) + d;
        const float* xp = xcs + n * 8;
        float acc = 0.f;
        #pragma unroll
        for (int i = 0; i < 7; ++i) acc += xp[i] * wp[i * DHH];
        hbuf[(hh * NN + n) * HSTRIDE + d] = acc;
    }
    __syncthreads();

    // ---- Phase 2: e_src, e_dst (288 rows, one per thread) ----
    if (tid < HH * NN) {
        int hh = tid / NN;
        const float* hp = hbuf + tid * HSTRIDE;
        const float* asp = aslds + hh * DHH;
        const float* adp = adlds + hh * DHH;
        float s = 0.f, dd = 0.f;
        #pragma unroll
        for (int d = 0; d < DHH; ++d) { float hv = hp[d]; s += hv * asp[d]; dd += hv * adp[d]; }
        es[tid] = s; ed[tid] = dd;
    }
    __syncthreads();

    // ---- Phase 3: attention row + PV + ELU + fused down-projection partial ----
    if (tid < HH * NN) {
        int hh = tid / NN, i = tid - hh * NN;
        float esi = es[tid];
        const float* edp = ed + hh * NN;
        const uint2 mrow = adjm[i];
        const float* hrow = hbuf + (hh * NN) * HSTRIDE;
        float s = 0.f;
        float acc[DHH];
        #pragma unroll
        for (int d = 0; d < DHH; ++d) acc[d] = 0.f;
        #pragma unroll
        for (int j = 0; j < NN; ++j) {
            float e = esi + edp[j];
            e = (e > 0.f) ? e : 0.2f * e;                 // leaky_relu 0.2
            float p = __expf(e);                          // no max-sub: logits O(1)
            const bool on = (j < 32) ? ((mrow.x >> j) & 1u) : ((mrow.y >> (j - 32)) & 1u);
            p = on ? p : 0.0f;                            // mask == exp(-1e9-m)==0
            s += p;
            const float* hj = hrow + j * HSTRIDE;
            float4 h0 = *reinterpret_cast<const float4*>(hj);
            float4 h1 = *reinterpret_cast<const float4*>(hj + 4);
            float h2 = hj[8];
            acc[0] += p * h0.x; acc[1] += p * h0.y; acc[2] += p * h0.z; acc[3] += p * h0.w;
            acc[4] += p * h1.x; acc[5] += p * h1.y; acc[6] += p * h1.z; acc[7] += p * h1.w;
            acc[8] += p * h2;
        }
        float inv = 1.0f / s;
        const float* wdp = wdlds + hh * DHH;
        float pdown = 0.f;
        #pragma unroll
        for (int d = 0; d < DHH; ++d) {
            float o = acc[d] * inv;
            o = (o > 0.f) ? o : (__expf(o) - 1.0f);       // elu
            pdown += o * wdp[d];
        }
        pd[i * 9 + hh] = pdown;
    }
    __syncthreads();

    // ---- Phase 4: down + feat = leaky_relu(concat(down, t), 0.01) ----
    if (tid < NN) {
        const float* pp = pd + tid * 9;
        float acc = bdlds[0];
        #pragma unroll
        for (int h = 0; h < HH; ++h) acc += pp[h];
        feat[tid] = (acc > 0.f) ? acc : 0.01f * acc;
    } else if (tid < 2 * NN) {
        float v = ts[tid - NN];
        feat[tid] = (v > 0.f) ? v : 0.01f * v;
    }
    __syncthreads();

    // ---- Phase 5: mu = feat @ W_mu + b_mu ----
    if (tid < ACTF) {
        float acc = bmulds[tid];
        #pragma unroll
        for (int k = 0; k < GATF; ++k) acc += feat[k] * wmulds[k * ACTF + tid];
        out[(size_t)b * ACTF + tid] = acc;
    }
}

extern "C" void kernel_launch(void* const* d_in, const int* in_sizes, int n_in,
                              void* d_out, int out_size, void* d_ws, size_t ws_size,
                              hipStream_t stream) {
    const float* x      = (const float*)d_in[0];
    const int*   adj    = (const int*)d_in[1];
    const float* W      = (const float*)d_in[2];
    const float* a_src  = (const float*)d_in[3];
    const float* a_dst  = (const float*)d_in[4];
    const float* W_down = (const float*)d_in[5];
    const float* b_down = (const float*)d_in[6];
    const float* W_mu   = (const float*)d_in[7];
    const float* b_mu   = (const float*)d_in[8];
    float* out = (float*)d_out;

    gnn_kernel<<<BB, NTH, 0, stream>>>(x, adj, W, a_src, a_dst, W_down, b_down, W_mu, b_mu, out);
}

// Round 5
// 76.865 us; speedup vs baseline: 1.5620x; 1.5399x over previous
//
#include <hip/hip_runtime.h>

typedef float v2f __attribute__((ext_vector_type(2)));

#define BB 8192
#define NN 36
#define INF_ 8
#define HH 8
#define DHH 9
#define GATF 72
#define ACTF 10
#define NTH 320
#define HSTRIDE 12
#define WSTRIDE 12
#define L2E 1.44269504088896f

__global__ __launch_bounds__(NTH, 6) void gnn_kernel(
    const float* __restrict__ x, const int* __restrict__ adj,
    const float* __restrict__ W, const float* __restrict__ a_src,
    const float* __restrict__ a_dst, const float* __restrict__ W_down,
    const float* __restrict__ b_down, const float* __restrict__ W_mu,
    const float* __restrict__ b_mu, float* __restrict__ out)
{
    const int b = blockIdx.x;
    const int tid = threadIdx.x;

    __shared__ float xcs[NN * 9];                        // xc, stride 9 (conflict-free)
    __shared__ float ts[NN];                             // t = x[:,:,4]
    __shared__ __align__(16) float hbuf[HH * NN * HSTRIDE];   // 13824 B
    __shared__ __align__(16) float edl[HH * NN];         // ed * log2e
    __shared__ uint2 adjm[NN];                           // row bitmasks
    __shared__ float pd[NN * 9];                         // partial down [i][h], stride 9
    __shared__ float feat[GATF];
    __shared__ __align__(16) float wlds[HH * 7 * WSTRIDE];  // W padded: [(h*7+k)*12 + d]
    __shared__ float aslds[HH * DHH];
    __shared__ float adlds[HH * DHH];
    __shared__ float wdlds[GATF];
    __shared__ float wmulds[GATF * ACTF];
    __shared__ float bdlds[1];
    __shared__ float bmulds[ACTF];

    // ---- Phase 0: stage inputs ----
    const float* xb = x + (size_t)b * (NN * INF_);
    if (tid < NN * INF_) {
        int n = tid >> 3, c = tid & 7;
        float v = xb[tid];
        if (c < 3) xcs[n * 9 + c] = v;
        else if (c > 3) xcs[n * 9 + (c - 1)] = v;
        if (c == 4) ts[n] = v;
    }
    {   // adjacency -> 36 row bitmasks on threads 256..291
        int i = tid - 256;
        if (i >= 0 && i < NN) {
            const int4* ap = reinterpret_cast<const int4*>(adj + i * NN);  // 144B rows, 16B-aligned
            unsigned int lo = 0u, hi = 0u;
            #pragma unroll
            for (int q = 0; q < 9; ++q) {
                int4 a4 = ap[q];
                const int base = q * 4;
                if (base + 0 < 32) { lo |= (a4.x > 0 ? 1u << (base + 0) : 0u); } else { hi |= (a4.x > 0 ? 1u << (base - 32) : 0u); }
                if (base + 1 < 32) { lo |= (a4.y > 0 ? 1u << (base + 1) : 0u); } else { hi |= (a4.y > 0 ? 1u << (base + 1 - 32) : 0u); }
                if (base + 2 < 32) { lo |= (a4.z > 0 ? 1u << (base + 2) : 0u); } else { hi |= (a4.z > 0 ? 1u << (base + 2 - 32) : 0u); }
                if (base + 3 < 32) { lo |= (a4.w > 0 ? 1u << (base + 3) : 0u); } else { hi |= (a4.w > 0 ? 1u << (base + 3 - 32) : 0u); }
            }
            adjm[i] = make_uint2(lo, hi);
        }
    }
    // W: global [(h*7+k)*9 + d] -> LDS [(h*7+k)*12 + d] (rows 16B-aligned)
    for (int idx = tid; idx < HH * 7 * DHH; idx += NTH) {
        int row = idx / DHH, d = idx - row * DHH;
        wlds[row * WSTRIDE + d] = W[idx];
    }
    if (tid < HH * DHH) { aslds[tid] = a_src[tid]; adlds[tid] = a_dst[tid]; }
    if (tid >= 128 && tid < 128 + GATF) wdlds[tid - 128] = W_down[tid - 128];
    for (int idx = tid; idx < GATF * ACTF; idx += NTH) wmulds[idx] = W_mu[idx];
    if (tid == 0) bdlds[0] = b_down[0];
    if (tid >= 64 && tid < 64 + ACTF) bmulds[tid - 64] = b_mu[tid - 64];
    __syncthreads();

    // ---- Phase 1+2 merged: one thread per (h,i) row computes h-row, es (reg), ed (LDS) ----
    const int hh = (tid < HH * NN) ? (tid / NN) : 0;
    const int i  = (tid < HH * NN) ? (tid - hh * NN) : 0;
    float esr = 0.f;
    if (tid < HH * NN) {
        const float* xp = xcs + i * 9;
        float h0=0.f,h1=0.f,h2=0.f,h3=0.f,h4=0.f,h5=0.f,h6=0.f,h7=0.f,h8=0.f;
        const float* wp = wlds + hh * 7 * WSTRIDE;
        #pragma unroll
        for (int k = 0; k < 7; ++k) {
            float xk = xp[k];
            const float* wr = wp + k * WSTRIDE;
            float4 wa = *reinterpret_cast<const float4*>(wr);
            float4 wb = *reinterpret_cast<const float4*>(wr + 4);
            float  wc = wr[8];
            h0 = fmaf(xk, wa.x, h0); h1 = fmaf(xk, wa.y, h1);
            h2 = fmaf(xk, wa.z, h2); h3 = fmaf(xk, wa.w, h3);
            h4 = fmaf(xk, wb.x, h4); h5 = fmaf(xk, wb.y, h5);
            h6 = fmaf(xk, wb.z, h6); h7 = fmaf(xk, wb.w, h7);
            h8 = fmaf(xk, wc, h8);
        }
        float* hp = hbuf + (hh * NN + i) * HSTRIDE;
        *reinterpret_cast<float4*>(hp)     = make_float4(h0, h1, h2, h3);
        *reinterpret_cast<float4*>(hp + 4) = make_float4(h4, h5, h6, h7);
        hp[8] = h8;
        const float* asp = aslds + hh * DHH;
        const float* adp = adlds + hh * DHH;
        float s = 0.f, dd = 0.f;
        s = fmaf(h0, asp[0], s); dd = fmaf(h0, adp[0], dd);
        s = fmaf(h1, asp[1], s); dd = fmaf(h1, adp[1], dd);
        s = fmaf(h2, asp[2], s); dd = fmaf(h2, adp[2], dd);
        s = fmaf(h3, asp[3], s); dd = fmaf(h3, adp[3], dd);
        s = fmaf(h4, asp[4], s); dd = fmaf(h4, adp[4], dd);
        s = fmaf(h5, asp[5], s); dd = fmaf(h5, adp[5], dd);
        s = fmaf(h6, asp[6], s); dd = fmaf(h6, adp[6], dd);
        s = fmaf(h7, asp[7], s); dd = fmaf(h7, adp[7], dd);
        s = fmaf(h8, asp[8], s); dd = fmaf(h8, adp[8], dd);
        esr = s * L2E;                    // prescaled by log2e
        edl[hh * NN + i] = dd * L2E;      // prescaled by log2e
    }
    __syncthreads();

    // ---- Phase 3: attention row + PV (pk_fma) + ELU + fused down partial ----
    if (tid < HH * NN) {
        const uint2 mrow = adjm[i];
        const float* hrow = hbuf + (hh * NN) * HSTRIDE;
        const float* edp = edl + hh * NN;
        v2f acc01 = {0.f, 0.f}, acc23 = {0.f, 0.f}, acc45 = {0.f, 0.f}, acc67 = {0.f, 0.f};
        float acc8 = 0.f, ssum = 0.f;

#define STEP(jj, ee) { \
        float s_ = esr + (ee); \
        float e_ = fmaxf(s_, 0.2f * s_);                 /* leaky (prescaled) */ \
        float p_ = __builtin_exp2f(e_); \
        unsigned bit_ = (((jj) < 32) ? (mrow.x >> (jj)) : (mrow.y >> ((jj) - 32))) & 1u; \
        p_ *= (float)bit_;                               /* mask: exact 0 */ \
        ssum += p_; \
        const float* hj_ = hrow + (jj) * HSTRIDE; \
        float4 ha_ = *reinterpret_cast<const float4*>(hj_); \
        float4 hb_ = *reinterpret_cast<const float4*>(hj_ + 4); \
        float  hc_ = hj_[8]; \
        v2f pp_ = {p_, p_}; \
        v2f h01_ = {ha_.x, ha_.y}, h23_ = {ha_.z, ha_.w}; \
        v2f h45_ = {hb_.x, hb_.y}, h67_ = {hb_.z, hb_.w}; \
        acc01 = __builtin_elementwise_fma(pp_, h01_, acc01); \
        acc23 = __builtin_elementwise_fma(pp_, h23_, acc23); \
        acc45 = __builtin_elementwise_fma(pp_, h45_, acc45); \
        acc67 = __builtin_elementwise_fma(pp_, h67_, acc67); \
        acc8 = fmaf(p_, hc_, acc8); \
    }

        #pragma unroll
        for (int q = 0; q < 9; ++q) {
            float4 e4 = *reinterpret_cast<const float4*>(edp + q * 4);  // broadcast, aligned
            STEP(4 * q + 0, e4.x);
            STEP(4 * q + 1, e4.y);
            STEP(4 * q + 2, e4.z);
            STEP(4 * q + 3, e4.w);
        }
#undef STEP

        float inv = 1.0f / ssum;
        const float* wdp = wdlds + hh * DHH;
        float pdown = 0.f;
#define EPI(val, dd_) { \
        float o_ = (val) * inv; \
        o_ = (o_ > 0.f) ? o_ : (__builtin_exp2f(o_ * L2E) - 1.0f);  /* elu */ \
        pdown = fmaf(o_, wdp[dd_], pdown); \
    }
        EPI(acc01.x, 0); EPI(acc01.y, 1); EPI(acc23.x, 2); EPI(acc23.y, 3);
        EPI(acc45.x, 4); EPI(acc45.y, 5); EPI(acc67.x, 6); EPI(acc67.y, 7);
        EPI(acc8, 8);
#undef EPI
        pd[i * 9 + hh] = pdown;
    }
    __syncthreads();

    // ---- Phase 4: down + feat = leaky_relu(concat(down, t), 0.01) ----
    if (tid < NN) {
        const float* pp = pd + tid * 9;
        float acc = bdlds[0];
        #pragma unroll
        for (int h = 0; h < HH; ++h) acc += pp[h];
        feat[tid] = (acc > 0.f) ? acc : 0.01f * acc;
    } else if (tid < 2 * NN) {
        float v = ts[tid - NN];
        feat[tid] = (v > 0.f) ? v : 0.01f * v;
    }
    __syncthreads();

    // ---- Phase 5: mu = feat @ W_mu + b_mu ----
    if (tid < ACTF) {
        float acc = bmulds[tid];
        #pragma unroll
        for (int k = 0; k < GATF; ++k) acc += feat[k] * wmulds[k * ACTF + tid];
        out[(size_t)b * ACTF + tid] = acc;
    }
}

extern "C" void kernel_launch(void* const* d_in, const int* in_sizes, int n_in,
                              void* d_out, int out_size, void* d_ws, size_t ws_size,
                              hipStream_t stream) {
    const float* x      = (const float*)d_in[0];
    const int*   adj    = (const int*)d_in[1];
    const float* W      = (const float*)d_in[2];
    const float* a_src  = (const float*)d_in[3];
    const float* a_dst  = (const float*)d_in[4];
    const float* W_down = (const float*)d_in[5];
    const float* b_down = (const float*)d_in[6];
    const float* W_mu   = (const float*)d_in[7];
    const float* b_mu   = (const float*)d_in[8];
    float* out = (float*)d_out;

    gnn_kernel<<<BB, NTH, 0, stream>>>(x, adj, W, a_src, a_dst, W_down, b_down, W_mu, b_mu, out);
}